// Round 11
// baseline (296.560 us; speedup 1.0000x reference)
//
#include <hip/hip_runtime.h>
#include <hip/hip_bf16.h>

using bf16 = __hip_bfloat16;

#define BATCH 16
#define NNODE 2000
#define DIM   128
#define ODIM  64
#define NLAYER 3
#define BN    (BATCH*NNODE)   // 32000
#define NCH   500             // chunks per batch (chunk size 4)
#define CKS2  4
#define SFX   502             // suffix-table entries per batch (NCH + 2 zero pads)
#define NSEG  25              // segments per batch (20 chunks each)
#define SEGC  20
#define PADKEY 0xFFFFFFFFFFFFFFFFull

// converted-input element offsets inside cvt buffer
#define OFF_COORDS 0
#define OFF_EW0    64000
#define OFF_EB0    64256
#define OFF_EW1    64384
#define OFF_EB1    80768
#define OFF_GW     80896
#define OFF_GA1    130048
#define OFF_GA2    130432
#define OFF_PW     130816
#define OFF_PB     139008
#define CVT_TOT    139072

// packed-weight offsets (ushort elements): [col][k] fragment order, hi plane then lo plane
// layer-0 slot holds Wfuse = enc_w1 @ gat_W[0] (encoder folded in)
#define PK_GAT(l)  (32768 + (l)*32768)     // 2*16384 each
#define PK_PROJ    131072                  // 2*8192
#define PK_TOT     147456

typedef __attribute__((ext_vector_type(8))) short bf16x8;
typedef __attribute__((ext_vector_type(4))) float f32x4;

__device__ __forceinline__ unsigned short f2bf(float f){
    union { float f; unsigned u; } x; x.f = f;
    unsigned r = (x.u + 0x7FFFu + ((x.u >> 16) & 1u)) >> 16;
    return (unsigned short)r;
}
__device__ __forceinline__ float bf2f(unsigned short h){
    union { unsigned u; float f; } x; x.u = ((unsigned)h) << 16;
    return x.f;
}
// monotone float -> uint transform (total order) and inverse
__device__ __forceinline__ unsigned ordu(float f){
    union { float f; unsigned u; } x; x.f = f;
    return (x.u & 0x80000000u) ? ~x.u : (x.u | 0x80000000u);
}
__device__ __forceinline__ float iordu(unsigned u){
    union { unsigned u; float f; } x;
    x.u = (u & 0x80000000u) ? (u ^ 0x80000000u) : ~u;
    return x.f;
}

struct InPtrs { const void* p[10]; };

// ------------- convert ALL inputs to fp32 (sniff embedded per block) ---------------
__global__ void convert_all_k(InPtrs in, float* __restrict__ dst, float* __restrict__ flag)
{
    __shared__ int scnt[256];
    const unsigned short* raw = (const unsigned short*)in.p[0];
    int t = threadIdx.x, c = 0;
    for (int k = t; k < 2048; k += 256){
        unsigned short u = raw[2*k];                 // first 8 KB, safe either dtype
        int e = (u >> 7) & 0xFF;
        if (e >= 100 && e <= 140) ++c;
    }
    scnt[t] = c;
    __syncthreads();
    for (int s = 128; s; s >>= 1){ if (t < s) scnt[t] += scnt[t+s]; __syncthreads(); }
    const bool isbf16 = (scnt[0] >= 1800);
    if (blockIdx.x == 0 && t == 0) flag[0] = isbf16 ? 1.0f : 0.0f;

    const int off[11] = {OFF_COORDS,OFF_EW0,OFF_EB0,OFF_EW1,OFF_EB1,
                         OFF_GW,OFF_GA1,OFF_GA2,OFF_PW,OFF_PB,CVT_TOT};
    int i = blockIdx.x*256 + t;
    if (i >= CVT_TOT) return;
    int seg = 0;
    #pragma unroll
    for (int s = 1; s < 10; ++s) if (i >= off[s]) seg = s;
    int li = i - off[seg];
    if (isbf16) dst[i] = __bfloat162float(((const bf16*)in.p[seg])[li]);
    else        dst[i] = ((const float*)in.p[seg])[li];
}

// ------------- prep: pack W layers 1,2 + proj to bf16 hi/lo; wa = W@a vectors ------
__global__ __launch_bounds__(256) void prep_k(const float* __restrict__ cvt,
                                              unsigned short* __restrict__ pk,
                                              float* __restrict__ wa)
{
    const int mi = blockIdx.x, t = threadIdx.x;
    if (mi < 3){
        const float* W; unsigned short* dst; int N;
        if (mi == 0)      { W = cvt + OFF_GW + 1*DIM*DIM;  dst = pk + PK_GAT(1); N = 128; }
        else if (mi == 1) { W = cvt + OFF_GW + 2*DIM*DIM;  dst = pk + PK_GAT(2); N = 128; }
        else              { W = cvt + OFF_PW;              dst = pk + PK_PROJ;   N = 64;  }
        const int tot = 128*N;
        unsigned short* dh = dst;
        unsigned short* dl = dst + tot;
        for (int e = t; e < tot; e += 256){
            int col = e >> 7, k = e & 127;            // dst layout [col][k]
            float v = W[k*N + col];
            unsigned short hb = f2bf(v);
            unsigned short lb = f2bf(v - bf2f(hb));
            dh[e] = hb;
            dl[e] = lb;
        }
    } else {
        // wa[l*256 + half*128 + r] = (gat_W[l] @ a_half[l])[r]
        for (int idx = t; idx < 3*256; idx += 256){
            const int l = idx >> 8, rem = idx & 255, half = rem >> 7, r = rem & 127;
            const float* W  = cvt + OFF_GW + l*DIM*DIM;
            const float* av = cvt + (half ? OFF_GA2 : OFF_GA1) + l*DIM;
            float s = 0.f;
            for (int c2 = 0; c2 < 128; ++c2) s = fmaf(W[r*128 + c2], av[c2], s);
            wa[l*256 + half*128 + r] = s;
        }
    }
}

// ------------- prep2: Wfuse = w1@W0 (packed), bfuse = b1@W0, u1/u2, s1/s2 ----------
__global__ __launch_bounds__(128) void prep2_k(const float* __restrict__ cvt,
    unsigned short* __restrict__ pk, const float* __restrict__ wa,
    float* __restrict__ u12, float* __restrict__ bfuse, float* __restrict__ su)
{
    const int b = blockIdx.x, t = threadIdx.x;
    const float* w1 = cvt + OFF_EW1;
    const float* W0 = cvt + OFF_GW;
    if (b < 128){
        float acc = 0.f;
        for (int d = 0; d < 128; ++d) acc = fmaf(w1[b*DIM + d], W0[d*DIM + t], acc);
        unsigned short hb = f2bf(acc), lb = f2bf(acc - bf2f(hb));
        unsigned short* dst = pk + PK_GAT(0);
        dst[t*128 + b]         = hb;      // [col=t][k=b] hi plane
        dst[16384 + t*128 + b] = lb;      // lo plane
    } else if (b == 128){
        const float* b1 = cvt + OFF_EB1;
        float acc = 0.f;
        for (int d = 0; d < 128; ++d) acc = fmaf(b1[d], W0[d*DIM + t], acc);
        bfuse[t] = acc;
        if (t < 2){
            float s = 0.f;
            for (int d = 0; d < 128; ++d) s = fmaf(b1[d], wa[t*128 + d], s);
            su[t] = s;
        }
    } else {
        float a1 = 0.f, a2 = 0.f;
        for (int d = 0; d < 128; ++d){
            float w = w1[t*DIM + d];
            a1 = fmaf(w, wa[d],       a1);
            a2 = fmaf(w, wa[128 + d], a2);
        }
        u12[t]       = a1;
        u12[128 + t] = a2;
    }
}

// ---- shared MFMA convention: A tile 64x128 staged as hi/lo bf16, XOR-swizzled -----
// LDS row stride 256 B; swizzle: byte_in_row ^= (row&7)<<4  (both write & read sides)

// ------------- layer-0 GAT: encoder folded in. A1 = relu(coords@w0+b0) inline ------
__global__ __launch_bounds__(256) void gat0mfma_k(const float* __restrict__ cvt,
    const unsigned short* __restrict__ pk, const float* __restrict__ u12,
    const float* __restrict__ su, const float* __restrict__ bfuse,
    float* __restrict__ Wh, float* __restrict__ e1p, float* __restrict__ e2p)
{
    __shared__ unsigned short sAh[64*128], sAl[64*128];
    const int t = threadIdx.x, r0 = blockIdx.x*64;
    const int wv = t >> 6, l = t & 63, lc = l & 15, lk = l >> 4;
    const unsigned short* ph = pk;
    const unsigned short* pl = pk + 16384;
    bf16x8 bh[2][4], bl[2][4];
    #pragma unroll
    for (int cg = 0; cg < 2; ++cg){
        const int col = wv*32 + cg*16 + lc;
        #pragma unroll
        for (int kc = 0; kc < 4; ++kc){
            const int k0 = kc*32 + lk*8;
            bh[cg][kc] = *(const bf16x8*)&ph[col*128 + k0];
            bl[cg][kc] = *(const bf16x8*)&pl[col*128 + k0];
        }
    }
    const int row = t >> 2, g = t & 3;
    const float* coords = cvt + OFF_COORDS;
    const float* w0  = cvt + OFF_EW0;
    const float* b0v = cvt + OFF_EB0;
    const int node = r0 + row;
    const float c0 = coords[2*node], c1 = coords[2*node+1];
    char* shb = (char*)sAh; char* slb = (char*)sAl;
    const int swz = (row & 7) << 4;
    float e1 = 0.f, e2 = 0.f;
    #pragma unroll
    for (int i = 0; i < 8; ++i){
        const int ch = g + i*4, k0 = ch*4;
        float4 wa0 = *(const float4*)&w0[k0];
        float4 wb0 = *(const float4*)&w0[DIM + k0];
        float4 bq  = *(const float4*)&b0v[k0];
        float4 v;
        v.x = fmaf(c0, wa0.x, fmaf(c1, wb0.x, bq.x)); v.x = v.x > 0.f ? v.x : 0.f;
        v.y = fmaf(c0, wa0.y, fmaf(c1, wb0.y, bq.y)); v.y = v.y > 0.f ? v.y : 0.f;
        v.z = fmaf(c0, wa0.z, fmaf(c1, wb0.z, bq.z)); v.z = v.z > 0.f ? v.z : 0.f;
        v.w = fmaf(c0, wa0.w, fmaf(c1, wb0.w, bq.w)); v.w = v.w > 0.f ? v.w : 0.f;
        float4 q1 = *(const float4*)&u12[k0];
        float4 q2 = *(const float4*)&u12[128 + k0];
        e1 = fmaf(v.x,q1.x, fmaf(v.y,q1.y, fmaf(v.z,q1.z, fmaf(v.w,q1.w, e1))));
        e2 = fmaf(v.x,q2.x, fmaf(v.y,q2.y, fmaf(v.z,q2.z, fmaf(v.w,q2.w, e2))));
        ushort4 hq, lq;
        hq.x = f2bf(v.x); lq.x = f2bf(v.x - bf2f(hq.x));
        hq.y = f2bf(v.y); lq.y = f2bf(v.y - bf2f(hq.y));
        hq.z = f2bf(v.z); lq.z = f2bf(v.z - bf2f(hq.z));
        hq.w = f2bf(v.w); lq.w = f2bf(v.w - bf2f(hq.w));
        const int bo = (ch*8) ^ swz;
        *(ushort4*)(shb + row*256 + bo) = hq;
        *(ushort4*)(slb + row*256 + bo) = lq;
    }
    e1 += __shfl_xor(e1, 1); e1 += __shfl_xor(e1, 2);
    e2 += __shfl_xor(e2, 1); e2 += __shfl_xor(e2, 2);
    if (g == 0){ e1p[r0 + row] = e1 + su[0]; e2p[r0 + row] = e2 + su[1]; }
    __syncthreads();
    f32x4 acc[4][2] = {};
    #pragma unroll
    for (int m = 0; m < 4; ++m){
        const int ar = m*16 + lc, asw = (ar & 7) << 4;
        #pragma unroll
        for (int kc = 0; kc < 4; ++kc){
            const int bo = (kc*64 + lk*16) ^ asw;
            bf16x8 ah = *(bf16x8*)(shb + ar*256 + bo);
            bf16x8 al = *(bf16x8*)(slb + ar*256 + bo);
            #pragma unroll
            for (int cg = 0; cg < 2; ++cg){
                acc[m][cg] = __builtin_amdgcn_mfma_f32_16x16x32_bf16(ah, bh[cg][kc], acc[m][cg], 0, 0, 0);
                acc[m][cg] = __builtin_amdgcn_mfma_f32_16x16x32_bf16(ah, bl[cg][kc], acc[m][cg], 0, 0, 0);
                acc[m][cg] = __builtin_amdgcn_mfma_f32_16x16x32_bf16(al, bh[cg][kc], acc[m][cg], 0, 0, 0);
            }
        }
    }
    #pragma unroll
    for (int m = 0; m < 4; ++m){
        const int rg = r0 + m*16 + lk*4;
        #pragma unroll
        for (int cg = 0; cg < 2; ++cg){
            const int col = wv*32 + cg*16 + lc;
            const float bb = bfuse[col];
            #pragma unroll
            for (int j = 0; j < 4; ++j) Wh[(size_t)(rg+j)*DIM + col] = acc[m][cg][j] + bb;
        }
    }
}

// ------------- GAT GEMM (layers 1,2): Wh = h @ W + e1/e2 via h@(W@a) ---------------
__global__ __launch_bounds__(256) void gatmfma_k(const float* __restrict__ A,
    const unsigned short* __restrict__ pk, const float* __restrict__ wa,
    float* __restrict__ Wh, float* __restrict__ e1p, float* __restrict__ e2p)
{
    __shared__ unsigned short sAh[64*128], sAl[64*128];
    const int t = threadIdx.x, r0 = blockIdx.x*64;
    const int wv = t >> 6, l = t & 63, lc = l & 15, lk = l >> 4;
    const unsigned short* ph = pk;
    const unsigned short* pl = pk + 16384;
    bf16x8 bh[2][4], bl[2][4];
    #pragma unroll
    for (int cg = 0; cg < 2; ++cg){
        const int col = wv*32 + cg*16 + lc;
        #pragma unroll
        for (int kc = 0; kc < 4; ++kc){
            const int k0 = kc*32 + lk*8;
            bh[cg][kc] = *(const bf16x8*)&ph[col*128 + k0];
            bl[cg][kc] = *(const bf16x8*)&pl[col*128 + k0];
        }
    }
    const int row = t >> 2, g = t & 3;
    const float* Ar = A + (size_t)(r0 + row)*DIM;
    char* shb = (char*)sAh; char* slb = (char*)sAl;
    const int swz = (row & 7) << 4;
    float e1 = 0.f, e2 = 0.f;
    #pragma unroll
    for (int i = 0; i < 8; ++i){
        const int ch = g + i*4;
        float4 a  = *(const float4*)&Ar[ch*4];
        float4 u1 = *(const float4*)&wa[ch*4];
        float4 u2 = *(const float4*)&wa[128 + ch*4];
        e1 = fmaf(a.x,u1.x, fmaf(a.y,u1.y, fmaf(a.z,u1.z, fmaf(a.w,u1.w, e1))));
        e2 = fmaf(a.x,u2.x, fmaf(a.y,u2.y, fmaf(a.z,u2.z, fmaf(a.w,u2.w, e2))));
        ushort4 hq, lq;
        hq.x = f2bf(a.x); lq.x = f2bf(a.x - bf2f(hq.x));
        hq.y = f2bf(a.y); lq.y = f2bf(a.y - bf2f(hq.y));
        hq.z = f2bf(a.z); lq.z = f2bf(a.z - bf2f(hq.z));
        hq.w = f2bf(a.w); lq.w = f2bf(a.w - bf2f(hq.w));
        const int bo = (ch*8) ^ swz;
        *(ushort4*)(shb + row*256 + bo) = hq;
        *(ushort4*)(slb + row*256 + bo) = lq;
    }
    e1 += __shfl_xor(e1, 1); e1 += __shfl_xor(e1, 2);
    e2 += __shfl_xor(e2, 1); e2 += __shfl_xor(e2, 2);
    if (g == 0){ e1p[r0 + row] = e1; e2p[r0 + row] = e2; }
    __syncthreads();
    f32x4 acc[4][2] = {};
    #pragma unroll
    for (int m = 0; m < 4; ++m){
        const int ar = m*16 + lc, asw = (ar & 7) << 4;
        #pragma unroll
        for (int kc = 0; kc < 4; ++kc){
            const int bo = (kc*64 + lk*16) ^ asw;
            bf16x8 ah = *(bf16x8*)(shb + ar*256 + bo);
            bf16x8 al = *(bf16x8*)(slb + ar*256 + bo);
            #pragma unroll
            for (int cg = 0; cg < 2; ++cg){
                acc[m][cg] = __builtin_amdgcn_mfma_f32_16x16x32_bf16(ah, bh[cg][kc], acc[m][cg], 0, 0, 0);
                acc[m][cg] = __builtin_amdgcn_mfma_f32_16x16x32_bf16(ah, bl[cg][kc], acc[m][cg], 0, 0, 0);
                acc[m][cg] = __builtin_amdgcn_mfma_f32_16x16x32_bf16(al, bh[cg][kc], acc[m][cg], 0, 0, 0);
            }
        }
    }
    #pragma unroll
    for (int m = 0; m < 4; ++m){
        const int rg = r0 + m*16 + lk*4;
        #pragma unroll
        for (int cg = 0; cg < 2; ++cg){
            const int col = wv*32 + cg*16 + lc;
            #pragma unroll
            for (int j = 0; j < 4; ++j) Wh[(size_t)(rg+j)*DIM + col] = acc[m][cg][j];
        }
    }
}

// ------------- final projection GEMM (split-bf16 MFMA), output dtype per flag ------
__global__ __launch_bounds__(256) void projmfma_k(const float* __restrict__ A,
    const unsigned short* __restrict__ pk, const float* __restrict__ bias,
    void* __restrict__ outp, const float* __restrict__ flag)
{
    __shared__ unsigned short sAh[64*128], sAl[64*128];
    const int t = threadIdx.x, r0 = blockIdx.x*64;
    const int wv = t >> 6, l = t & 63, lc = l & 15, lk = l >> 4;
    const unsigned short* ph = pk;
    const unsigned short* pl = pk + 8192;
    bf16x8 bh[4], bl[4];
    const int col = wv*16 + lc;
    #pragma unroll
    for (int kc = 0; kc < 4; ++kc){
        const int k0 = kc*32 + lk*8;
        bh[kc] = *(const bf16x8*)&ph[col*128 + k0];
        bl[kc] = *(const bf16x8*)&pl[col*128 + k0];
    }
    const int row = t >> 2, g = t & 3;
    const float* Ar = A + (size_t)(r0 + row)*DIM;
    char* shb = (char*)sAh; char* slb = (char*)sAl;
    const int swz = (row & 7) << 4;
    #pragma unroll
    for (int i = 0; i < 8; ++i){
        const int ch = g + i*4;
        float4 a = *(const float4*)&Ar[ch*4];
        ushort4 hq, lq;
        hq.x = f2bf(a.x); lq.x = f2bf(a.x - bf2f(hq.x));
        hq.y = f2bf(a.y); lq.y = f2bf(a.y - bf2f(hq.y));
        hq.z = f2bf(a.z); lq.z = f2bf(a.z - bf2f(hq.z));
        hq.w = f2bf(a.w); lq.w = f2bf(a.w - bf2f(hq.w));
        const int bo = (ch*8) ^ swz;
        *(ushort4*)(shb + row*256 + bo) = hq;
        *(ushort4*)(slb + row*256 + bo) = lq;
    }
    __syncthreads();
    f32x4 acc[4] = {};
    #pragma unroll
    for (int m = 0; m < 4; ++m){
        const int ar = m*16 + lc, asw = (ar & 7) << 4;
        #pragma unroll
        for (int kc = 0; kc < 4; ++kc){
            const int bo = (kc*64 + lk*16) ^ asw;
            bf16x8 ah = *(bf16x8*)(shb + ar*256 + bo);
            bf16x8 al = *(bf16x8*)(slb + ar*256 + bo);
            acc[m] = __builtin_amdgcn_mfma_f32_16x16x32_bf16(ah, bh[kc], acc[m], 0, 0, 0);
            acc[m] = __builtin_amdgcn_mfma_f32_16x16x32_bf16(ah, bl[kc], acc[m], 0, 0, 0);
            acc[m] = __builtin_amdgcn_mfma_f32_16x16x32_bf16(al, bh[kc], acc[m], 0, 0, 0);
        }
    }
    const float bb = bias[col];
    const bool isbf = (flag[0] != 0.0f);
    #pragma unroll
    for (int m = 0; m < 4; ++m){
        const int rg = r0 + m*16 + lk*4;
        #pragma unroll
        for (int j = 0; j < 4; ++j){
            float v = acc[m][j] + bb;
            size_t p = (size_t)(rg+j)*ODIM + col;
            if (isbf) ((bf16*)outp)[p] = __float2bfloat16(v);
            else      ((float*)outp)[p] = v;
        }
    }
}

// ------------- sortA: per-256-sublist bitonic (8 sublists/batch, 128 blocks) -------
// Replaces the 16-block monolithic bitonic (6% GPU util, ~66 stages). Unique u64
// keys (value<<32|idx); sublist 7 padded to 256 with PADKEY.
#define WAVE_FENCE() __asm__ volatile("" ::: "memory")
__global__ __launch_bounds__(128) void sortA_k(const float* __restrict__ e2p,
                                               unsigned long long* __restrict__ skeys)
{
    __shared__ unsigned long long kv[256];
    const int b = blockIdx.x >> 3, s = blockIdx.x & 7, t = threadIdx.x;
    const int base = b*NNODE, g0 = s*256;
    #pragma unroll
    for (int q = 0; q < 2; ++q){
        int i = t + q*128;
        int gi = g0 + i;
        kv[i] = (gi < NNODE) ? (((unsigned long long)ordu(e2p[base+gi]) << 32) | (unsigned)gi)
                             : PADKEY;
    }
    __syncthreads();
    // sizes 2..128: strides <= 64 -> wave-local (wave0 covers [0,128), wave1 [128,256))
    #pragma unroll 1
    for (int size = 2; size <= 128; size <<= 1){
        #pragma unroll 1
        for (int stride = size >> 1; stride > 0; stride >>= 1){
            int i = 2*t - (t & (stride-1));
            int j = i + stride;
            bool asc = ((i & size) == 0);
            unsigned long long ki = kv[i], kj = kv[j];
            bool sw = asc ? (ki > kj) : (ki < kj);
            if (sw){ kv[i] = kj; kv[j] = ki; }
            WAVE_FENCE();
        }
    }
    __syncthreads();
    // size 256: stride 128 (cross-wave), then wave-local strides; asc everywhere
    {
        unsigned long long ki = kv[t], kj = kv[t + 128];
        if (ki > kj){ kv[t] = kj; kv[t + 128] = ki; }
        __syncthreads();
    }
    #pragma unroll 1
    for (int stride = 64; stride > 0; stride >>= 1){
        int i = 2*t - (t & (stride-1));
        int j = i + stride;
        unsigned long long ki = kv[i], kj = kv[j];
        if (ki > kj){ kv[i] = kj; kv[j] = ki; }
        WAVE_FENCE();
    }
    __syncthreads();
    #pragma unroll
    for (int q = 0; q < 2; ++q){
        int i = t + q*128;
        skeys[(size_t)b*2048 + g0 + i] = kv[i];
    }
}

// ------------- sortB: merge-rank. rank = own pos + sum of countLess over other -----
// sublists (binsearch in LDS); lo = sum of countLess(threshold) over all sublists —
// the merged binsearch decomposes exactly, merged array never materialized.
// Identical permutation/outputs to the old monolithic bitonic (unique keys).
__global__ __launch_bounds__(256) void sortB_k(const unsigned long long* __restrict__ skeys,
    const float* __restrict__ e1p, int* __restrict__ sidx, float* __restrict__ wp,
    float* __restrict__ wn, float* __restrict__ sps, float* __restrict__ sns,
    int* __restrict__ loArr)
{
    __shared__ __align__(16) unsigned long long kv[2048];
    __shared__ float smax[4];
    const int b = blockIdx.x >> 3, s = blockIdx.x & 7, t = threadIdx.x;
    const int base = b*NNODE;
    float pm = -3.0e38f;
    #pragma unroll
    for (int q = 0; q < 8; ++q){
        int i = t + q*256;
        unsigned long long k = skeys[(size_t)b*2048 + i];
        kv[i] = k;
        if (k != PADKEY) pm = fmaxf(pm, iordu((unsigned)(k >> 32)));
    }
    #pragma unroll
    for (int m = 32; m; m >>= 1) pm = fmaxf(pm, __shfl_xor(pm, m));
    if ((t & 63) == 0) smax[t >> 6] = pm;
    __syncthreads();
    const float mx = fmaxf(fmaxf(smax[0], smax[1]), fmaxf(smax[2], smax[3]));

    // rank-scatter own sublist element t
    {
        unsigned long long k = kv[s*256 + t];
        if (k != PADKEY){
            int rank = t;                      // local rank in own sorted sublist
            #pragma unroll 1
            for (int s2 = 0; s2 < 8; ++s2){
                if (s2 == s) continue;
                const int o = s2*256;
                int lo2 = 0, hi2 = 256;
                while (lo2 < hi2){ int mid = (lo2+hi2)>>1; if (kv[o+mid] < k) lo2 = mid+1; else hi2 = mid; }
                rank += lo2;
            }
            float val = iordu((unsigned)(k >> 32));
            sidx[base + rank] = (int)(k & 0xFFFFFFFFull);
            wp  [base + rank] = __expf(val - mx);
            wn  [base + rank] = __expf(0.2f*(val - mx));
        }
    }
    // per-row threshold lo + softmax weights (250 rows per block)
    if (t < 250){
        const int i = s*250 + t;
        float e1v = e1p[base + i];
        float sv = e1v + mx;
        float m = (sv >= 0.f) ? sv : 0.2f*sv;
        sps[base + i] = __expf(sv - m);
        sns[base + i] = __expf(0.2f*sv - m);
        const unsigned long long tk = ((unsigned long long)ordu(-e1v)) << 32;
        int lo = 0;
        #pragma unroll 1
        for (int s2 = 0; s2 < 8; ++s2){
            const int o = s2*256;
            int lo2 = 0, hi2 = 256;
            while (lo2 < hi2){ int mid = (lo2+hi2)>>1; if (kv[o+mid] < tk) lo2 = mid+1; else hi2 = mid; }
            lo += lo2;
        }
        loArr[base + i] = lo;
    }
}

// ------------- chunkSums: per-4-row-chunk weighted totals over sorted order --------
__global__ __launch_bounds__(128) void chunkSums_k(const float* __restrict__ Wh,
    const int* __restrict__ sidx, const float* __restrict__ wp, const float* __restrict__ wn,
    float* __restrict__ chunkP, float* __restrict__ chunkN,
    float* __restrict__ schunkP, float* __restrict__ schunkN)
{
    const int b = blockIdx.x / NCH, c = blockIdx.x % NCH, d = threadIdx.x;
    const int base = b*NNODE;
    float sp=0.f, sn=0.f, ssp=0.f, ssn=0.f;
    #pragma unroll
    for (int r = c*CKS2; r < c*CKS2 + CKS2; ++r){
        int j = sidx[base + r];
        float whv = Wh[((size_t)base + j)*DIM + d];
        float wpv = wp[base + r], wnv = wn[base + r];
        sp = fmaf(wpv, whv, sp);  sn = fmaf(wnv, whv, sn);
        ssp += wpv;  ssn += wnv;
    }
    const int idx = b*NCH + c;
    chunkP[(size_t)idx*DIM + d] = sp;
    chunkN[(size_t)idx*DIM + d] = sn;
    if (d == 0){ schunkP[idx] = ssp; schunkN[idx] = ssn; }
}

// ------------- segTot: per-segment (20-chunk) totals from chunk tables -------------
__global__ __launch_bounds__(128) void segTot_k(
    const float* __restrict__ chunkP, const float* __restrict__ chunkN,
    const float* __restrict__ schunkP, const float* __restrict__ schunkN,
    float* __restrict__ segP, float* __restrict__ segN,
    float* __restrict__ ssegP, float* __restrict__ ssegN)
{
    const int b = blockIdx.x / NSEG, seg = blockIdx.x % NSEG, d = threadIdx.x;
    const int c0 = seg*SEGC;
    float aP = 0.f, aN = 0.f;
    #pragma unroll
    for (int k = 0; k < SEGC; ++k){
        aP += chunkP[((size_t)b*NCH + c0 + k)*DIM + d];
        aN += chunkN[((size_t)b*NCH + c0 + k)*DIM + d];
    }
    segP[((size_t)b*NSEG + seg)*DIM + d] = aP;
    segN[((size_t)b*NSEG + seg)*DIM + d] = aN;
    if (d == 0){
        float sP = 0.f, sN = 0.f;
        #pragma unroll
        for (int k = 0; k < SEGC; ++k){
            sP += schunkP[b*NCH + c0 + k];
            sN += schunkN[b*NCH + c0 + k];
        }
        ssegP[b*NSEG + seg] = sP;
        ssegN[b*NSEG + seg] = sN;
    }
}

// ------------- sfxFill: level 2 — tail-of-segments + within-segment suffix walk ----
__global__ __launch_bounds__(128) void sfxFill_k(
    const float* __restrict__ chunkP, const float* __restrict__ chunkN,
    const float* __restrict__ schunkP, const float* __restrict__ schunkN,
    const float* __restrict__ segP, const float* __restrict__ segN,
    const float* __restrict__ ssegP, const float* __restrict__ ssegN,
    float* __restrict__ sfxP, float* __restrict__ sfxN,
    float* __restrict__ sfxSP, float* __restrict__ sfxSN)
{
    const int b = blockIdx.x / NSEG, seg = blockIdx.x % NSEG, d = threadIdx.x;
    const size_t sb = (size_t)b*SFX;
    float aP = 0.f, aN = 0.f;
    for (int s = seg + 1; s < NSEG; ++s){
        aP += segP[((size_t)b*NSEG + s)*DIM + d];
        aN += segN[((size_t)b*NSEG + s)*DIM + d];
    }
    const int c0 = seg*SEGC;
    #pragma unroll
    for (int k = SEGC-1; k >= 0; --k){
        aP += chunkP[((size_t)b*NCH + c0 + k)*DIM + d];
        aN += chunkN[((size_t)b*NCH + c0 + k)*DIM + d];
        sfxP[(sb + c0 + k)*DIM + d] = aP;
        sfxN[(sb + c0 + k)*DIM + d] = aN;
    }
    if (seg == NSEG-1){
        sfxP[(sb + NCH    )*DIM + d] = 0.f;
        sfxP[(sb + NCH + 1)*DIM + d] = 0.f;
        sfxN[(sb + NCH    )*DIM + d] = 0.f;
        sfxN[(sb + NCH + 1)*DIM + d] = 0.f;
    }
    if (d == 0){
        float sP = 0.f, sN = 0.f;
        for (int s = seg + 1; s < NSEG; ++s){
            sP += ssegP[b*NSEG + s];
            sN += ssegN[b*NSEG + s];
        }
        #pragma unroll
        for (int k = SEGC-1; k >= 0; --k){
            sP += schunkP[b*NCH + c0 + k];
            sN += schunkN[b*NCH + c0 + k];
            sfxSP[b*SFX + c0 + k] = sP;
            sfxSN[b*SFX + c0 + k] = sN;
        }
        if (seg == NSEG-1){
            sfxSP[b*SFX + NCH] = 0.f;  sfxSP[b*SFX + NCH + 1] = 0.f;
            sfxSN[b*SFX + NCH] = 0.f;  sfxSN[b*SFX + NCH + 1] = 0.f;
        }
    }
}

// ------------- out4: 16 fixed output rows/block; <=4-row on-the-fly suffix ---------
__global__ __launch_bounds__(128) void out4_k(const float* __restrict__ Wh,
    const int* __restrict__ sidx, const float* __restrict__ wp, const float* __restrict__ wn,
    const float* __restrict__ sfxP, const float* __restrict__ sfxN,
    const float* __restrict__ sfxSP, const float* __restrict__ sfxSN,
    const float* __restrict__ sps, const float* __restrict__ sns,
    const int* __restrict__ loArr, float* __restrict__ h)
{
    __shared__ int   slo[16];
    __shared__ float ssp[16], ssn[16];
    const int b = blockIdx.x / 125, g16 = blockIdx.x % 125, d = threadIdx.x;
    const int base = b*NNODE, row0 = g16*16;

    if (d < 16){
        int row = base + row0 + d;
        slo[d] = loArr[row];
        ssp[d] = sps[row];
        ssn[d] = sns[row];
    }
    __syncthreads();

    const size_t sb = (size_t)b*SFX;
    const float totN  = sfxN[sb*DIM + d];      // suffix from chunk 0 = batch total
    const float totSN = sfxSN[b*SFX];

    #pragma unroll 4
    for (int k = 0; k < 16; ++k){
        const int lo = slo[k];
        const int cl = lo >> 2;                 // chunk containing lo (<= NCH)
        float suffP = sfxP[(sb + cl + 1)*DIM + d];
        float suffN = sfxN[(sb + cl + 1)*DIM + d];
        float sSP   = sfxSP[b*SFX + cl + 1];
        float sSN   = sfxSN[b*SFX + cl + 1];
        int rend = (cl + 1)*CKS2; if (rend > NNODE) rend = NNODE;
        #pragma unroll 1
        for (int r = lo; r < rend; ++r){
            int j = sidx[base + r];
            float whv = Wh[((size_t)base + j)*DIM + d];
            float wpv = wp[base + r], wnv = wn[base + r];
            suffP = fmaf(wpv, whv, suffP);
            suffN = fmaf(wnv, whv, suffN);
            sSP += wpv;  sSN += wnv;
        }
        const float spsv = ssp[k], snsv = ssn[k];
        float numer = spsv*suffP + snsv*(totN - suffN);
        float Z     = spsv*sSP   + snsv*(totSN - sSN);
        float v = numer / Z;
        h[((size_t)base + row0 + k)*DIM + d] = (v > 0.f) ? v : ((v == v) ? 0.f : v);
    }
}

extern "C" void kernel_launch(void* const* d_in, const int* in_sizes, int n_in,
                              void* d_out, int out_size, void* d_ws, size_t ws_size,
                              hipStream_t stream)
{
    (void)in_sizes; (void)n_in; (void)out_size; (void)ws_size;

    float* f = (float*)d_ws;
    float* flag    = f;  f += 4;
    float* cvt     = f;  f += CVT_TOT;                 // 0.56 MB
    float* h       = f;  f += (size_t)BN*DIM;          // 16.4 MB
    float* Wh      = f;  f += (size_t)BN*DIM;          // 16.4 MB
    float* chunkP  = f;  f += (size_t)BATCH*NCH*DIM;   // 4.1 MB
    float* chunkN  = f;  f += (size_t)BATCH*NCH*DIM;   // 4.1 MB
    float* sfxP    = f;  f += (size_t)BATCH*SFX*DIM;   // 4.1 MB
    float* sfxN    = f;  f += (size_t)BATCH*SFX*DIM;   // 4.1 MB
    float* segP    = f;  f += (size_t)BATCH*NSEG*DIM;  // 0.2 MB
    float* segN    = f;  f += (size_t)BATCH*NSEG*DIM;  // 0.2 MB
    float* schunkP = f;  f += BATCH*NCH;
    float* schunkN = f;  f += BATCH*NCH;
    float* sfxSP   = f;  f += BATCH*SFX;
    float* sfxSN   = f;  f += BATCH*SFX;
    float* ssegP   = f;  f += BATCH*NSEG;
    float* ssegN   = f;  f += BATCH*NSEG;
    float* e1p     = f;  f += BN;
    float* e2p     = f;  f += BN;
    float* wp      = f;  f += BN;
    float* wn      = f;  f += BN;
    float* sps     = f;  f += BN;
    float* sns     = f;  f += BN;
    int*   sidx    = (int*)f;  f += BN;
    int*   loArr   = (int*)f;  f += BN;
    unsigned long long* skeys = (unsigned long long*)f;  f += BATCH*2048*2;  // 262 KB, 8B-aligned
    unsigned short* pk = (unsigned short*)f;             // 16B-aligned
    float* wa      = (float*)(pk + PK_TOT);              // 3 layers x {wa1,wa2}[128]
    float* u12     = wa + 768;                           // u1[128], u2[128]
    float* bfuse   = u12 + 256;                          // b1@W0 [128]
    float* su      = bfuse + 128;                        // s1, s2

    // 1. convert all inputs to fp32 (sniff embedded)
    InPtrs ip;
    for (int i = 0; i < 10; ++i) ip.p[i] = d_in[i];
    convert_all_k<<<(CVT_TOT+255)/256, 256, 0, stream>>>(ip, cvt, flag);

    // 2. pack W layers 1,2 + proj; wa = W@a.  3. fused-encoder weights for layer 0.
    prep_k<<<4, 256, 0, stream>>>(cvt, pk, wa);
    prep2_k<<<130, 128, 0, stream>>>(cvt, pk, wa, u12, bfuse, su);

    // 4. GAT layers (exact separable-softmax factorization); layer 0 folds encoder
    for (int l = 0; l < NLAYER; ++l){
        if (l == 0)
            gat0mfma_k<<<BN/64, 256, 0, stream>>>(cvt, pk + PK_GAT(0), u12, su, bfuse,
                                                  Wh, e1p, e2p);
        else
            gatmfma_k<<<BN/64, 256, 0, stream>>>(h, pk + PK_GAT(l), wa + l*256, Wh, e1p, e2p);
        sortA_k<<<BATCH*8, 128, 0, stream>>>(e2p, skeys);
        sortB_k<<<BATCH*8, 256, 0, stream>>>(skeys, e1p, sidx, wp, wn, sps, sns, loArr);
        chunkSums_k<<<BATCH*NCH, DIM, 0, stream>>>(Wh, sidx, wp, wn,
                                                   chunkP, chunkN, schunkP, schunkN);
        segTot_k<<<BATCH*NSEG, 128, 0, stream>>>(chunkP, chunkN, schunkP, schunkN,
                                                 segP, segN, ssegP, ssegN);
        sfxFill_k<<<BATCH*NSEG, 128, 0, stream>>>(chunkP, chunkN, schunkP, schunkN,
                                                  segP, segN, ssegP, ssegN,
                                                  sfxP, sfxN, sfxSP, sfxSN);
        out4_k<<<BATCH*125, DIM, 0, stream>>>(Wh, sidx, wp, wn, sfxP, sfxN, sfxSP, sfxSN,
                                              sps, sns, loArr, h);
    }

    // 5. projection (split-bf16 MFMA), output dtype per flag
    projmfma_k<<<BN/64, 256, 0, stream>>>(h, pk + PK_PROJ, cvt + OFF_PB, d_out, flag);
}

// Round 12
// 293.731 us; speedup vs baseline: 1.0096x; 1.0096x over previous
//
#include <hip/hip_runtime.h>
#include <hip/hip_bf16.h>

using bf16 = __hip_bfloat16;

#define BATCH 16
#define NNODE 2000
#define DIM   128
#define ODIM  64
#define NLAYER 3
#define BN    (BATCH*NNODE)   // 32000
#define NCH   500             // chunks per batch (chunk size 4)
#define CKS2  4
#define SFX   502             // suffix-table entries per batch (NCH + 2 zero pads)
#define NSEG  25              // segments per batch (20 chunks each)
#define SEGC  20

// converted-input element offsets inside cvt buffer
#define OFF_COORDS 0
#define OFF_EW0    64000
#define OFF_EB0    64256
#define OFF_EW1    64384
#define OFF_EB1    80768
#define OFF_GW     80896
#define OFF_GA1    130048
#define OFF_GA2    130432
#define OFF_PW     130816
#define OFF_PB     139008
#define CVT_TOT    139072

// packed-weight offsets (ushort elements): [col][k] fragment order, hi plane then lo plane
// layer-0 slot holds Wfuse = enc_w1 @ gat_W[0] (encoder folded in)
#define PK_GAT(l)  (32768 + (l)*32768)     // 2*16384 each
#define PK_PROJ    131072                  // 2*8192
#define PK_TOT     147456

typedef __attribute__((ext_vector_type(8))) short bf16x8;
typedef __attribute__((ext_vector_type(4))) float f32x4;

__device__ __forceinline__ unsigned short f2bf(float f){
    union { float f; unsigned u; } x; x.f = f;
    unsigned r = (x.u + 0x7FFFu + ((x.u >> 16) & 1u)) >> 16;
    return (unsigned short)r;
}
__device__ __forceinline__ float bf2f(unsigned short h){
    union { unsigned u; float f; } x; x.u = ((unsigned)h) << 16;
    return x.f;
}
// monotone float -> uint transform (total order) and inverse
__device__ __forceinline__ unsigned ordu(float f){
    union { float f; unsigned u; } x; x.f = f;
    return (x.u & 0x80000000u) ? ~x.u : (x.u | 0x80000000u);
}
__device__ __forceinline__ float iordu(unsigned u){
    union { unsigned u; float f; } x;
    x.u = (u & 0x80000000u) ? (u ^ 0x80000000u) : ~u;
    return x.f;
}

struct InPtrs { const void* p[10]; };

// ------------- convert ALL inputs to fp32 (sniff embedded per block) ---------------
__global__ void convert_all_k(InPtrs in, float* __restrict__ dst, float* __restrict__ flag)
{
    __shared__ int scnt[256];
    const unsigned short* raw = (const unsigned short*)in.p[0];
    int t = threadIdx.x, c = 0;
    for (int k = t; k < 2048; k += 256){
        unsigned short u = raw[2*k];                 // first 8 KB, safe either dtype
        int e = (u >> 7) & 0xFF;
        if (e >= 100 && e <= 140) ++c;
    }
    scnt[t] = c;
    __syncthreads();
    for (int s = 128; s; s >>= 1){ if (t < s) scnt[t] += scnt[t+s]; __syncthreads(); }
    const bool isbf16 = (scnt[0] >= 1800);
    if (blockIdx.x == 0 && t == 0) flag[0] = isbf16 ? 1.0f : 0.0f;

    const int off[11] = {OFF_COORDS,OFF_EW0,OFF_EB0,OFF_EW1,OFF_EB1,
                         OFF_GW,OFF_GA1,OFF_GA2,OFF_PW,OFF_PB,CVT_TOT};
    int i = blockIdx.x*256 + t;
    if (i >= CVT_TOT) return;
    int seg = 0;
    #pragma unroll
    for (int s = 1; s < 10; ++s) if (i >= off[s]) seg = s;
    int li = i - off[seg];
    if (isbf16) dst[i] = __bfloat162float(((const bf16*)in.p[seg])[li]);
    else        dst[i] = ((const float*)in.p[seg])[li];
}

// ------------- prep_all: weight packing + wa + fused-encoder weights (one kernel) --
// blocks 0..3  : pack W layers 1,2 + proj (bf16 hi/lo) ; block 3 also writes wa
// blocks 4..131: Wfuse = w1@W0 rows (b = blk-4)
// block 132    : bfuse = b1@W0 and su (recomputes layer-0 wa locally -> no race)
// block 133    : u12 (recomputes layer-0 wa locally)
__global__ __launch_bounds__(256) void prep_all_k(const float* __restrict__ cvt,
    unsigned short* __restrict__ pk, float* __restrict__ wa,
    float* __restrict__ u12, float* __restrict__ bfuse, float* __restrict__ su)
{
    const int blk = blockIdx.x, t = threadIdx.x;
    if (blk < 3){
        const float* W; unsigned short* dst; int N;
        if (blk == 0)      { W = cvt + OFF_GW + 1*DIM*DIM;  dst = pk + PK_GAT(1); N = 128; }
        else if (blk == 1) { W = cvt + OFF_GW + 2*DIM*DIM;  dst = pk + PK_GAT(2); N = 128; }
        else               { W = cvt + OFF_PW;              dst = pk + PK_PROJ;   N = 64;  }
        const int tot = 128*N;
        unsigned short* dh = dst;
        unsigned short* dl = dst + tot;
        for (int e = t; e < tot; e += 256){
            int col = e >> 7, k = e & 127;            // dst layout [col][k]
            float v = W[k*N + col];
            unsigned short hb = f2bf(v);
            unsigned short lb = f2bf(v - bf2f(hb));
            dh[e] = hb;
            dl[e] = lb;
        }
        return;
    }
    if (blk == 3){
        // wa[l*256 + half*128 + r] = (gat_W[l] @ a_half[l])[r]
        for (int idx = t; idx < 3*256; idx += 256){
            const int l = idx >> 8, rem = idx & 255, half = rem >> 7, r = rem & 127;
            const float* W  = cvt + OFF_GW + l*DIM*DIM;
            const float* av = cvt + (half ? OFF_GA2 : OFF_GA1) + l*DIM;
            float s = 0.f;
            for (int c2 = 0; c2 < 128; ++c2) s = fmaf(W[r*128 + c2], av[c2], s);
            wa[l*256 + half*128 + r] = s;
        }
        return;
    }
    const int b = blk - 4;
    const float* w1 = cvt + OFF_EW1;
    const float* W0 = cvt + OFF_GW;
    if (b < 128){
        if (t < 128){
            float acc = 0.f;
            for (int d = 0; d < 128; ++d) acc = fmaf(w1[b*DIM + d], W0[d*DIM + t], acc);
            unsigned short hb = f2bf(acc), lb = f2bf(acc - bf2f(hb));
            unsigned short* dst = pk + PK_GAT(0);
            dst[t*128 + b]         = hb;      // [col=t][k=b] hi plane
            dst[16384 + t*128 + b] = lb;      // lo plane
        }
        return;
    }
    // blocks 132/133 need layer-0 wa; recompute locally (same FMA order as block 3)
    __shared__ float waL[256];
    if (t < 128){
        const float* a1v = cvt + OFF_GA1;
        const float* a2v = cvt + OFF_GA2;
        float s1 = 0.f, s2 = 0.f;
        for (int c2 = 0; c2 < 128; ++c2){
            float w = W0[t*128 + c2];
            s1 = fmaf(w, a1v[c2], s1);
            s2 = fmaf(w, a2v[c2], s2);
        }
        waL[t]       = s1;
        waL[128 + t] = s2;
    }
    __syncthreads();
    if (b == 128){
        if (t < 128){
            const float* b1 = cvt + OFF_EB1;
            float acc = 0.f;
            for (int d = 0; d < 128; ++d) acc = fmaf(b1[d], W0[d*DIM + t], acc);
            bfuse[t] = acc;
            if (t < 2){
                float s = 0.f;
                for (int d = 0; d < 128; ++d) s = fmaf(b1[d], waL[t*128 + d], s);
                su[t] = s;
            }
        }
    } else { // b == 129
        if (t < 128){
            float a1 = 0.f, a2 = 0.f;
            for (int d = 0; d < 128; ++d){
                float w = w1[t*DIM + d];
                a1 = fmaf(w, waL[d],       a1);
                a2 = fmaf(w, waL[128 + d], a2);
            }
            u12[t]       = a1;
            u12[128 + t] = a2;
        }
    }
}

// ---- shared MFMA convention: A tile 64x128 staged as hi/lo bf16, XOR-swizzled -----
// LDS row stride 256 B; swizzle: byte_in_row ^= (row&7)<<4  (both write & read sides)

// ------------- layer-0 GAT: encoder folded in. A1 = relu(coords@w0+b0) inline ------
__global__ __launch_bounds__(256) void gat0mfma_k(const float* __restrict__ cvt,
    const unsigned short* __restrict__ pk, const float* __restrict__ u12,
    const float* __restrict__ su, const float* __restrict__ bfuse,
    float* __restrict__ Wh, float* __restrict__ e1p, float* __restrict__ e2p)
{
    __shared__ unsigned short sAh[64*128], sAl[64*128];
    const int t = threadIdx.x, r0 = blockIdx.x*64;
    const int wv = t >> 6, l = t & 63, lc = l & 15, lk = l >> 4;
    const unsigned short* ph = pk;
    const unsigned short* pl = pk + 16384;
    bf16x8 bh[2][4], bl[2][4];
    #pragma unroll
    for (int cg = 0; cg < 2; ++cg){
        const int col = wv*32 + cg*16 + lc;
        #pragma unroll
        for (int kc = 0; kc < 4; ++kc){
            const int k0 = kc*32 + lk*8;
            bh[cg][kc] = *(const bf16x8*)&ph[col*128 + k0];
            bl[cg][kc] = *(const bf16x8*)&pl[col*128 + k0];
        }
    }
    const int row = t >> 2, g = t & 3;
    const float* coords = cvt + OFF_COORDS;
    const float* w0  = cvt + OFF_EW0;
    const float* b0v = cvt + OFF_EB0;
    const int node = r0 + row;
    const float c0 = coords[2*node], c1 = coords[2*node+1];
    char* shb = (char*)sAh; char* slb = (char*)sAl;
    const int swz = (row & 7) << 4;
    float e1 = 0.f, e2 = 0.f;
    #pragma unroll
    for (int i = 0; i < 8; ++i){
        const int ch = g + i*4, k0 = ch*4;
        float4 wa0 = *(const float4*)&w0[k0];
        float4 wb0 = *(const float4*)&w0[DIM + k0];
        float4 bq  = *(const float4*)&b0v[k0];
        float4 v;
        v.x = fmaf(c0, wa0.x, fmaf(c1, wb0.x, bq.x)); v.x = v.x > 0.f ? v.x : 0.f;
        v.y = fmaf(c0, wa0.y, fmaf(c1, wb0.y, bq.y)); v.y = v.y > 0.f ? v.y : 0.f;
        v.z = fmaf(c0, wa0.z, fmaf(c1, wb0.z, bq.z)); v.z = v.z > 0.f ? v.z : 0.f;
        v.w = fmaf(c0, wa0.w, fmaf(c1, wb0.w, bq.w)); v.w = v.w > 0.f ? v.w : 0.f;
        float4 q1 = *(const float4*)&u12[k0];
        float4 q2 = *(const float4*)&u12[128 + k0];
        e1 = fmaf(v.x,q1.x, fmaf(v.y,q1.y, fmaf(v.z,q1.z, fmaf(v.w,q1.w, e1))));
        e2 = fmaf(v.x,q2.x, fmaf(v.y,q2.y, fmaf(v.z,q2.z, fmaf(v.w,q2.w, e2))));
        ushort4 hq, lq;
        hq.x = f2bf(v.x); lq.x = f2bf(v.x - bf2f(hq.x));
        hq.y = f2bf(v.y); lq.y = f2bf(v.y - bf2f(hq.y));
        hq.z = f2bf(v.z); lq.z = f2bf(v.z - bf2f(hq.z));
        hq.w = f2bf(v.w); lq.w = f2bf(v.w - bf2f(hq.w));
        const int bo = (ch*8) ^ swz;
        *(ushort4*)(shb + row*256 + bo) = hq;
        *(ushort4*)(slb + row*256 + bo) = lq;
    }
    e1 += __shfl_xor(e1, 1); e1 += __shfl_xor(e1, 2);
    e2 += __shfl_xor(e2, 1); e2 += __shfl_xor(e2, 2);
    if (g == 0){ e1p[r0 + row] = e1 + su[0]; e2p[r0 + row] = e2 + su[1]; }
    __syncthreads();
    f32x4 acc[4][2] = {};
    #pragma unroll
    for (int m = 0; m < 4; ++m){
        const int ar = m*16 + lc, asw = (ar & 7) << 4;
        #pragma unroll
        for (int kc = 0; kc < 4; ++kc){
            const int bo = (kc*64 + lk*16) ^ asw;
            bf16x8 ah = *(bf16x8*)(shb + ar*256 + bo);
            bf16x8 al = *(bf16x8*)(slb + ar*256 + bo);
            #pragma unroll
            for (int cg = 0; cg < 2; ++cg){
                acc[m][cg] = __builtin_amdgcn_mfma_f32_16x16x32_bf16(ah, bh[cg][kc], acc[m][cg], 0, 0, 0);
                acc[m][cg] = __builtin_amdgcn_mfma_f32_16x16x32_bf16(ah, bl[cg][kc], acc[m][cg], 0, 0, 0);
                acc[m][cg] = __builtin_amdgcn_mfma_f32_16x16x32_bf16(al, bh[cg][kc], acc[m][cg], 0, 0, 0);
            }
        }
    }
    #pragma unroll
    for (int m = 0; m < 4; ++m){
        const int rg = r0 + m*16 + lk*4;
        #pragma unroll
        for (int cg = 0; cg < 2; ++cg){
            const int col = wv*32 + cg*16 + lc;
            const float bb = bfuse[col];
            #pragma unroll
            for (int j = 0; j < 4; ++j) Wh[(size_t)(rg+j)*DIM + col] = acc[m][cg][j] + bb;
        }
    }
}

// ------------- GAT GEMM (layers 1,2): Wh = h @ W + e1/e2 via h@(W@a) ---------------
__global__ __launch_bounds__(256) void gatmfma_k(const float* __restrict__ A,
    const unsigned short* __restrict__ pk, const float* __restrict__ wa,
    float* __restrict__ Wh, float* __restrict__ e1p, float* __restrict__ e2p)
{
    __shared__ unsigned short sAh[64*128], sAl[64*128];
    const int t = threadIdx.x, r0 = blockIdx.x*64;
    const int wv = t >> 6, l = t & 63, lc = l & 15, lk = l >> 4;
    const unsigned short* ph = pk;
    const unsigned short* pl = pk + 16384;
    bf16x8 bh[2][4], bl[2][4];
    #pragma unroll
    for (int cg = 0; cg < 2; ++cg){
        const int col = wv*32 + cg*16 + lc;
        #pragma unroll
        for (int kc = 0; kc < 4; ++kc){
            const int k0 = kc*32 + lk*8;
            bh[cg][kc] = *(const bf16x8*)&ph[col*128 + k0];
            bl[cg][kc] = *(const bf16x8*)&pl[col*128 + k0];
        }
    }
    const int row = t >> 2, g = t & 3;
    const float* Ar = A + (size_t)(r0 + row)*DIM;
    char* shb = (char*)sAh; char* slb = (char*)sAl;
    const int swz = (row & 7) << 4;
    float e1 = 0.f, e2 = 0.f;
    #pragma unroll
    for (int i = 0; i < 8; ++i){
        const int ch = g + i*4;
        float4 a  = *(const float4*)&Ar[ch*4];
        float4 u1 = *(const float4*)&wa[ch*4];
        float4 u2 = *(const float4*)&wa[128 + ch*4];
        e1 = fmaf(a.x,u1.x, fmaf(a.y,u1.y, fmaf(a.z,u1.z, fmaf(a.w,u1.w, e1))));
        e2 = fmaf(a.x,u2.x, fmaf(a.y,u2.y, fmaf(a.z,u2.z, fmaf(a.w,u2.w, e2))));
        ushort4 hq, lq;
        hq.x = f2bf(a.x); lq.x = f2bf(a.x - bf2f(hq.x));
        hq.y = f2bf(a.y); lq.y = f2bf(a.y - bf2f(hq.y));
        hq.z = f2bf(a.z); lq.z = f2bf(a.z - bf2f(hq.z));
        hq.w = f2bf(a.w); lq.w = f2bf(a.w - bf2f(hq.w));
        const int bo = (ch*8) ^ swz;
        *(ushort4*)(shb + row*256 + bo) = hq;
        *(ushort4*)(slb + row*256 + bo) = lq;
    }
    e1 += __shfl_xor(e1, 1); e1 += __shfl_xor(e1, 2);
    e2 += __shfl_xor(e2, 1); e2 += __shfl_xor(e2, 2);
    if (g == 0){ e1p[r0 + row] = e1; e2p[r0 + row] = e2; }
    __syncthreads();
    f32x4 acc[4][2] = {};
    #pragma unroll
    for (int m = 0; m < 4; ++m){
        const int ar = m*16 + lc, asw = (ar & 7) << 4;
        #pragma unroll
        for (int kc = 0; kc < 4; ++kc){
            const int bo = (kc*64 + lk*16) ^ asw;
            bf16x8 ah = *(bf16x8*)(shb + ar*256 + bo);
            bf16x8 al = *(bf16x8*)(slb + ar*256 + bo);
            #pragma unroll
            for (int cg = 0; cg < 2; ++cg){
                acc[m][cg] = __builtin_amdgcn_mfma_f32_16x16x32_bf16(ah, bh[cg][kc], acc[m][cg], 0, 0, 0);
                acc[m][cg] = __builtin_amdgcn_mfma_f32_16x16x32_bf16(ah, bl[cg][kc], acc[m][cg], 0, 0, 0);
                acc[m][cg] = __builtin_amdgcn_mfma_f32_16x16x32_bf16(al, bh[cg][kc], acc[m][cg], 0, 0, 0);
            }
        }
    }
    #pragma unroll
    for (int m = 0; m < 4; ++m){
        const int rg = r0 + m*16 + lk*4;
        #pragma unroll
        for (int cg = 0; cg < 2; ++cg){
            const int col = wv*32 + cg*16 + lc;
            #pragma unroll
            for (int j = 0; j < 4; ++j) Wh[(size_t)(rg+j)*DIM + col] = acc[m][cg][j];
        }
    }
}

// ------------- final projection GEMM (split-bf16 MFMA), output dtype per flag ------
__global__ __launch_bounds__(256) void projmfma_k(const float* __restrict__ A,
    const unsigned short* __restrict__ pk, const float* __restrict__ bias,
    void* __restrict__ outp, const float* __restrict__ flag)
{
    __shared__ unsigned short sAh[64*128], sAl[64*128];
    const int t = threadIdx.x, r0 = blockIdx.x*64;
    const int wv = t >> 6, l = t & 63, lc = l & 15, lk = l >> 4;
    const unsigned short* ph = pk;
    const unsigned short* pl = pk + 8192;
    bf16x8 bh[4], bl[4];
    const int col = wv*16 + lc;
    #pragma unroll
    for (int kc = 0; kc < 4; ++kc){
        const int k0 = kc*32 + lk*8;
        bh[kc] = *(const bf16x8*)&ph[col*128 + k0];
        bl[kc] = *(const bf16x8*)&pl[col*128 + k0];
    }
    const int row = t >> 2, g = t & 3;
    const float* Ar = A + (size_t)(r0 + row)*DIM;
    char* shb = (char*)sAh; char* slb = (char*)sAl;
    const int swz = (row & 7) << 4;
    #pragma unroll
    for (int i = 0; i < 8; ++i){
        const int ch = g + i*4;
        float4 a = *(const float4*)&Ar[ch*4];
        ushort4 hq, lq;
        hq.x = f2bf(a.x); lq.x = f2bf(a.x - bf2f(hq.x));
        hq.y = f2bf(a.y); lq.y = f2bf(a.y - bf2f(hq.y));
        hq.z = f2bf(a.z); lq.z = f2bf(a.z - bf2f(hq.z));
        hq.w = f2bf(a.w); lq.w = f2bf(a.w - bf2f(hq.w));
        const int bo = (ch*8) ^ swz;
        *(ushort4*)(shb + row*256 + bo) = hq;
        *(ushort4*)(slb + row*256 + bo) = lq;
    }
    __syncthreads();
    f32x4 acc[4] = {};
    #pragma unroll
    for (int m = 0; m < 4; ++m){
        const int ar = m*16 + lc, asw = (ar & 7) << 4;
        #pragma unroll
        for (int kc = 0; kc < 4; ++kc){
            const int bo = (kc*64 + lk*16) ^ asw;
            bf16x8 ah = *(bf16x8*)(shb + ar*256 + bo);
            bf16x8 al = *(bf16x8*)(slb + ar*256 + bo);
            acc[m] = __builtin_amdgcn_mfma_f32_16x16x32_bf16(ah, bh[kc], acc[m], 0, 0, 0);
            acc[m] = __builtin_amdgcn_mfma_f32_16x16x32_bf16(ah, bl[kc], acc[m], 0, 0, 0);
            acc[m] = __builtin_amdgcn_mfma_f32_16x16x32_bf16(al, bh[kc], acc[m], 0, 0, 0);
        }
    }
    const float bb = bias[col];
    const bool isbf = (flag[0] != 0.0f);
    #pragma unroll
    for (int m = 0; m < 4; ++m){
        const int rg = r0 + m*16 + lk*4;
        #pragma unroll
        for (int j = 0; j < 4; ++j){
            float v = acc[m][j] + bb;
            size_t p = (size_t)(rg+j)*ODIM + col;
            if (isbf) ((bf16*)outp)[p] = __float2bfloat16(v);
            else      ((float*)outp)[p] = v;
        }
    }
}

// ------------- sortF: bitonic sort + per-row threshold (loArr) + sps/sns -----------
#define WAVE_FENCE() __asm__ volatile("" ::: "memory")
__global__ void sortF_k(const float* __restrict__ e2p, const float* __restrict__ e1p,
    int* __restrict__ sidx, float* __restrict__ wp, float* __restrict__ wn,
    float* __restrict__ sps, float* __restrict__ sns, int* __restrict__ loArr)
{
    __shared__ unsigned long long kv[2048];
    const int b = blockIdx.x, t = threadIdx.x;   // 1024 threads
    for (int i = t; i < 2048; i += 1024)
        kv[i] = (i < NNODE) ? (((unsigned long long)ordu(e2p[b*NNODE + i]) << 32) | (unsigned)i)
                            : 0xFFFFFFFFFFFFFFFFull;
    __syncthreads();

    #pragma unroll 1
    for (int size = 2; size <= 128; size <<= 1){
        #pragma unroll 1
        for (int stride = size >> 1; stride > 0; stride >>= 1){
            int i = 2*t - (t & (stride-1));
            int j = i + stride;
            bool asc = ((i & size) == 0);
            unsigned long long ki = kv[i], kj = kv[j];
            bool sw = asc ? (ki > kj) : (ki < kj);
            if (sw){ kv[i] = kj; kv[j] = ki; }
            WAVE_FENCE();
        }
    }
    __syncthreads();

    #pragma unroll 1
    for (int size = 256; size <= 2048; size <<= 1){
        #pragma unroll 1
        for (int stride = size >> 1; stride >= 128; stride >>= 1){
            int i = 2*t - (t & (stride-1));
            int j = i + stride;
            bool asc = ((i & size) == 0);
            unsigned long long ki = kv[i], kj = kv[j];
            bool sw = asc ? (ki > kj) : (ki < kj);
            if (sw){ kv[i] = kj; kv[j] = ki; }
            __syncthreads();
        }
        #pragma unroll 1
        for (int stride = 64; stride > 0; stride >>= 1){
            int i = 2*t - (t & (stride-1));
            int j = i + stride;
            bool asc = ((i & size) == 0);
            unsigned long long ki = kv[i], kj = kv[j];
            bool sw = asc ? (ki > kj) : (ki < kj);
            if (sw){ kv[i] = kj; kv[j] = ki; }
            WAVE_FENCE();
        }
        __syncthreads();
    }

    const float mx = iordu((unsigned)(kv[NNODE-1] >> 32));
    for (int i = t; i < NNODE; i += 1024){
        unsigned long long key = kv[i];
        float val = iordu((unsigned)(key >> 32));
        sidx[b*NNODE+i] = (int)(key & 0xFFFFFFFFull);
        wp  [b*NNODE+i] = __expf(val - mx);
        wn  [b*NNODE+i] = __expf(0.2f*(val - mx));
    }
    // per-row threshold + softmax weights (binsearch over sorted keys in LDS)
    #pragma unroll
    for (int q = 0; q < 2; ++q){
        const int i = t + q*1024;
        if (i < NNODE){
            float e1v = e1p[b*NNODE + i];
            float s = e1v + mx;
            float m = (s >= 0.f) ? s : 0.2f*s;
            sps[b*NNODE + i] = __expf(s - m);
            sns[b*NNODE + i] = __expf(0.2f*s - m);
            unsigned tt = ordu(-e1v);
            int lo = 0, hi = NNODE;
            while (lo < hi){
                int mid = (lo + hi) >> 1;
                if ((unsigned)(kv[mid] >> 32) < tt) lo = mid + 1; else hi = mid;
            }
            loArr[b*NNODE + i] = lo;
        }
    }
}

// ------------- chunkSeg: fused chunk sums + segment totals (one Wh gather) ---------
// Block (b,seg), 256 thr: half h (t>>7) handles chunks c0+10h .. c0+10h+9 with
// d = t&127. Seg totals combined across halves via LDS (one re-association).
__global__ __launch_bounds__(256) void chunkSeg_k(const float* __restrict__ Wh,
    const int* __restrict__ sidx, const float* __restrict__ wp, const float* __restrict__ wn,
    float* __restrict__ chunkP, float* __restrict__ chunkN,
    float* __restrict__ schunkP, float* __restrict__ schunkN,
    float* __restrict__ segP, float* __restrict__ segN,
    float* __restrict__ ssegP, float* __restrict__ ssegN)
{
    __shared__ float segbP[2][128], segbN[2][128];
    __shared__ float ssegb[2][2];
    const int b = blockIdx.x / NSEG, seg = blockIdx.x % NSEG;
    const int t = threadIdx.x, d = t & 127, hf = t >> 7;
    const int base = b*NNODE, c0 = seg*SEGC + hf*10;
    float aP = 0.f, aN = 0.f, saP = 0.f, saN = 0.f;
    #pragma unroll 1
    for (int k = 0; k < 10; ++k){
        const int c = c0 + k;
        float sp=0.f, sn=0.f, ssp=0.f, ssn=0.f;
        #pragma unroll
        for (int r = c*CKS2; r < c*CKS2 + CKS2; ++r){
            int j = sidx[base + r];
            float whv = Wh[((size_t)base + j)*DIM + d];
            float wpv = wp[base + r], wnv = wn[base + r];
            sp = fmaf(wpv, whv, sp);  sn = fmaf(wnv, whv, sn);
            ssp += wpv;  ssn += wnv;
        }
        const int idx = b*NCH + c;
        chunkP[(size_t)idx*DIM + d] = sp;
        chunkN[(size_t)idx*DIM + d] = sn;
        aP += sp;  aN += sn;
        if (d == 0){ schunkP[idx] = ssp; schunkN[idx] = ssn; saP += ssp; saN += ssn; }
    }
    segbP[hf][d] = aP;
    segbN[hf][d] = aN;
    if (d == 0){ ssegb[hf][0] = saP; ssegb[hf][1] = saN; }
    __syncthreads();
    if (hf == 0){
        segP[((size_t)b*NSEG + seg)*DIM + d] = segbP[0][d] + segbP[1][d];
        segN[((size_t)b*NSEG + seg)*DIM + d] = segbN[0][d] + segbN[1][d];
        if (d == 0){
            ssegP[b*NSEG + seg] = ssegb[0][0] + ssegb[1][0];
            ssegN[b*NSEG + seg] = ssegb[0][1] + ssegb[1][1];
        }
    }
}

// ------------- sfxFill: level 2 — tail-of-segments + within-segment suffix walk ----
__global__ __launch_bounds__(128) void sfxFill_k(
    const float* __restrict__ chunkP, const float* __restrict__ chunkN,
    const float* __restrict__ schunkP, const float* __restrict__ schunkN,
    const float* __restrict__ segP, const float* __restrict__ segN,
    const float* __restrict__ ssegP, const float* __restrict__ ssegN,
    float* __restrict__ sfxP, float* __restrict__ sfxN,
    float* __restrict__ sfxSP, float* __restrict__ sfxSN)
{
    const int b = blockIdx.x / NSEG, seg = blockIdx.x % NSEG, d = threadIdx.x;
    const size_t sb = (size_t)b*SFX;
    float aP = 0.f, aN = 0.f;
    for (int s = seg + 1; s < NSEG; ++s){
        aP += segP[((size_t)b*NSEG + s)*DIM + d];
        aN += segN[((size_t)b*NSEG + s)*DIM + d];
    }
    const int c0 = seg*SEGC;
    #pragma unroll
    for (int k = SEGC-1; k >= 0; --k){
        aP += chunkP[((size_t)b*NCH + c0 + k)*DIM + d];
        aN += chunkN[((size_t)b*NCH + c0 + k)*DIM + d];
        sfxP[(sb + c0 + k)*DIM + d] = aP;
        sfxN[(sb + c0 + k)*DIM + d] = aN;
    }
    if (seg == NSEG-1){
        sfxP[(sb + NCH    )*DIM + d] = 0.f;
        sfxP[(sb + NCH + 1)*DIM + d] = 0.f;
        sfxN[(sb + NCH    )*DIM + d] = 0.f;
        sfxN[(sb + NCH + 1)*DIM + d] = 0.f;
    }
    if (d == 0){
        float sP = 0.f, sN = 0.f;
        for (int s = seg + 1; s < NSEG; ++s){
            sP += ssegP[b*NSEG + s];
            sN += ssegN[b*NSEG + s];
        }
        #pragma unroll
        for (int k = SEGC-1; k >= 0; --k){
            sP += schunkP[b*NCH + c0 + k];
            sN += schunkN[b*NCH + c0 + k];
            sfxSP[b*SFX + c0 + k] = sP;
            sfxSN[b*SFX + c0 + k] = sN;
        }
        if (seg == NSEG-1){
            sfxSP[b*SFX + NCH] = 0.f;  sfxSP[b*SFX + NCH + 1] = 0.f;
            sfxSN[b*SFX + NCH] = 0.f;  sfxSN[b*SFX + NCH + 1] = 0.f;
        }
    }
}

// ------------- out4: 16 fixed output rows/block; <=4-row on-the-fly suffix ---------
__global__ __launch_bounds__(128) void out4_k(const float* __restrict__ Wh,
    const int* __restrict__ sidx, const float* __restrict__ wp, const float* __restrict__ wn,
    const float* __restrict__ sfxP, const float* __restrict__ sfxN,
    const float* __restrict__ sfxSP, const float* __restrict__ sfxSN,
    const float* __restrict__ sps, const float* __restrict__ sns,
    const int* __restrict__ loArr, float* __restrict__ h)
{
    __shared__ int   slo[16];
    __shared__ float ssp[16], ssn[16];
    const int b = blockIdx.x / 125, g16 = blockIdx.x % 125, d = threadIdx.x;
    const int base = b*NNODE, row0 = g16*16;

    if (d < 16){
        int row = base + row0 + d;
        slo[d] = loArr[row];
        ssp[d] = sps[row];
        ssn[d] = sns[row];
    }
    __syncthreads();

    const size_t sb = (size_t)b*SFX;
    const float totN  = sfxN[sb*DIM + d];      // suffix from chunk 0 = batch total
    const float totSN = sfxSN[b*SFX];

    #pragma unroll 4
    for (int k = 0; k < 16; ++k){
        const int lo = slo[k];
        const int cl = lo >> 2;                 // chunk containing lo (<= NCH)
        float suffP = sfxP[(sb + cl + 1)*DIM + d];
        float suffN = sfxN[(sb + cl + 1)*DIM + d];
        float sSP   = sfxSP[b*SFX + cl + 1];
        float sSN   = sfxSN[b*SFX + cl + 1];
        int rend = (cl + 1)*CKS2; if (rend > NNODE) rend = NNODE;
        #pragma unroll 1
        for (int r = lo; r < rend; ++r){
            int j = sidx[base + r];
            float whv = Wh[((size_t)base + j)*DIM + d];
            float wpv = wp[base + r], wnv = wn[base + r];
            suffP = fmaf(wpv, whv, suffP);
            suffN = fmaf(wnv, whv, suffN);
            sSP += wpv;  sSN += wnv;
        }
        const float spsv = ssp[k], snsv = ssn[k];
        float numer = spsv*suffP + snsv*(totN - suffN);
        float Z     = spsv*sSP   + snsv*(totSN - sSN);
        float v = numer / Z;
        h[((size_t)base + row0 + k)*DIM + d] = (v > 0.f) ? v : ((v == v) ? 0.f : v);
    }
}

extern "C" void kernel_launch(void* const* d_in, const int* in_sizes, int n_in,
                              void* d_out, int out_size, void* d_ws, size_t ws_size,
                              hipStream_t stream)
{
    (void)in_sizes; (void)n_in; (void)out_size; (void)ws_size;

    float* f = (float*)d_ws;
    float* flag    = f;  f += 4;
    float* cvt     = f;  f += CVT_TOT;                 // 0.56 MB
    float* h       = f;  f += (size_t)BN*DIM;          // 16.4 MB
    float* Wh      = f;  f += (size_t)BN*DIM;          // 16.4 MB
    float* chunkP  = f;  f += (size_t)BATCH*NCH*DIM;   // 4.1 MB
    float* chunkN  = f;  f += (size_t)BATCH*NCH*DIM;   // 4.1 MB
    float* sfxP    = f;  f += (size_t)BATCH*SFX*DIM;   // 4.1 MB
    float* sfxN    = f;  f += (size_t)BATCH*SFX*DIM;   // 4.1 MB
    float* segP    = f;  f += (size_t)BATCH*NSEG*DIM;  // 0.2 MB
    float* segN    = f;  f += (size_t)BATCH*NSEG*DIM;  // 0.2 MB
    float* schunkP = f;  f += BATCH*NCH;
    float* schunkN = f;  f += BATCH*NCH;
    float* sfxSP   = f;  f += BATCH*SFX;
    float* sfxSN   = f;  f += BATCH*SFX;
    float* ssegP   = f;  f += BATCH*NSEG;
    float* ssegN   = f;  f += BATCH*NSEG;
    float* e1p     = f;  f += BN;
    float* e2p     = f;  f += BN;
    float* wp      = f;  f += BN;
    float* wn      = f;  f += BN;
    float* sps     = f;  f += BN;
    float* sns     = f;  f += BN;
    int*   sidx    = (int*)f;  f += BN;
    int*   loArr   = (int*)f;  f += BN;
    unsigned short* pk = (unsigned short*)f;             // 16B-aligned
    float* wa      = (float*)(pk + PK_TOT);              // 3 layers x {wa1,wa2}[128]
    float* u12     = wa + 768;                           // u1[128], u2[128]
    float* bfuse   = u12 + 256;                          // b1@W0 [128]
    float* su      = bfuse + 128;                        // s1, s2

    // 1. convert all inputs to fp32 (sniff embedded)
    InPtrs ip;
    for (int i = 0; i < 10; ++i) ip.p[i] = d_in[i];
    convert_all_k<<<(CVT_TOT+255)/256, 256, 0, stream>>>(ip, cvt, flag);

    // 2. all weight prep in one kernel (pack, wa, fused-encoder weights)
    prep_all_k<<<134, 256, 0, stream>>>(cvt, pk, wa, u12, bfuse, su);

    // 3. GAT layers (exact separable-softmax factorization); layer 0 folds encoder
    for (int l = 0; l < NLAYER; ++l){
        if (l == 0)
            gat0mfma_k<<<BN/64, 256, 0, stream>>>(cvt, pk + PK_GAT(0), u12, su, bfuse,
                                                  Wh, e1p, e2p);
        else
            gatmfma_k<<<BN/64, 256, 0, stream>>>(h, pk + PK_GAT(l), wa + l*256, Wh, e1p, e2p);
        sortF_k<<<BATCH, 1024, 0, stream>>>(e2p, e1p, sidx, wp, wn, sps, sns, loArr);
        chunkSeg_k<<<BATCH*NSEG, 256, 0, stream>>>(Wh, sidx, wp, wn,
                                                   chunkP, chunkN, schunkP, schunkN,
                                                   segP, segN, ssegP, ssegN);
        sfxFill_k<<<BATCH*NSEG, 128, 0, stream>>>(chunkP, chunkN, schunkP, schunkN,
                                                  segP, segN, ssegP, ssegN,
                                                  sfxP, sfxN, sfxSP, sfxSN);
        out4_k<<<BATCH*125, DIM, 0, stream>>>(Wh, sidx, wp, wn, sfxP, sfxN, sfxSP, sfxSN,
                                              sps, sns, loArr, h);
    }

    // 4. projection (split-bf16 MFMA), output dtype per flag
    projmfma_k<<<BN/64, 256, 0, stream>>>(h, pk + PK_PROJ, cvt + OFF_PB, d_out, flag);
}